// Round 2
// baseline (663.913 us; speedup 1.0000x reference)
//
#include <hip/hip_runtime.h>

// SGGM: out[131072,768] = concat(h_node[b,i], h_node[b,j], h_edge[b,i,j]) @ W + bias
// B=32, N=128, H=128, E_PER=4096 -> M=131072, K=384, NOUT=768
// (resubmission — round 1 failed on GPU acquisition timeout, no data)

#define NNODE 128
#define HDIM  128
#define KDIM  384
#define NOUT  768
#define BM    128
#define BN    128
#define BK    64
#define NKITER 6   // 384/64

typedef __attribute__((ext_vector_type(4))) float f32x4;
typedef __attribute__((ext_vector_type(8))) short bf16x8;

static __device__ __forceinline__ short f2b(float f) {
    return __builtin_bit_cast(short, (__bf16)f);  // v_cvt RNE
}

__global__ void prep_kernel(const float* __restrict__ W, short* __restrict__ Wt) {
    // Wt[n][k] = bf16(W[k][n]);  W is [384][768]
    int n = blockIdx.x;
    for (int k = threadIdx.x; k < KDIM; k += 256) {
        Wt[n * KDIM + k] = f2b(W[k * NOUT + n]);
    }
}

__global__ __launch_bounds__(256) void gemm_kernel(
    const float* __restrict__ h_node, const float* __restrict__ h_edge,
    const int* __restrict__ pl, const short* __restrict__ Wt,
    const float* __restrict__ bias, float* __restrict__ out) {

    __shared__ int rowOff[3][BM];
    __shared__ __align__(16) short Abuf[BM * BK];  // 16 KB, XOR-swizzled
    __shared__ __align__(16) short Bbuf[BN * BK];  // 16 KB, XOR-swizzled

    const int tid = threadIdx.x;
    const int mBase = (int)(blockIdx.x & 1023) * BM;   // 1024 m-blocks
    const int nBase = (int)(blockIdx.x >> 10) * BN;    // 6 n-blocks; same-XCD per m

    if (tid < BM) {
        int e = mBase + tid;
        int b  = pl[3 * e + 0];
        int ii = pl[3 * e + 1];
        int jj = pl[3 * e + 2];
        rowOff[0][tid] = (b * NNODE + ii) * HDIM;                  // h_node[b,i]
        rowOff[1][tid] = (b * NNODE + jj) * HDIM;                  // h_node[b,j]
        rowOff[2][tid] = ((b * NNODE + ii) * NNODE + jj) * HDIM;   // h_edge[b,i,j]
    }
    __syncthreads();

    const int lane = tid & 63;
    const int wid  = tid >> 6;
    const int wm   = wid & 1;    // wave m-half (0..1)
    const int wn   = wid >> 1;   // wave n-half (0..1)
    const int r    = lane & 15;
    const int g    = lane >> 4;

    // staging decomposition: 1024 16B-chunks per tile, 4 per thread
    const int srow = tid >> 3;   // rows srow, srow+32, srow+64, srow+96
    const int sc   = tid & 7;    // 16B chunk within row (8 chunks of 8 bf16)

    f32x4 acc[4][4];
    #pragma unroll
    for (int a = 0; a < 4; ++a)
        #pragma unroll
        for (int b2 = 0; b2 < 4; ++b2)
            acc[a][b2] = (f32x4){0.f, 0.f, 0.f, 0.f};

    char* Ab = (char*)Abuf;
    char* Bb = (char*)Bbuf;

    for (int kk = 0; kk < NKITER; ++kk) {
        const int seg  = kk >> 1;                       // 0,0,1,1,2,2
        const float* gbase = (seg < 2) ? h_node : h_edge;
        const int koff = (kk & 1) * BK;                 // offset within 128-seg

        // ---- issue global loads early (overlap with prev compute) ----
        f32x4 ax[4], ay[4];
        #pragma unroll
        for (int t = 0; t < 4; ++t) {
            int row = srow + t * 32;
            const float* p = gbase + rowOff[seg][row] + koff + sc * 8;
            ax[t] = *(const f32x4*)p;
            ay[t] = *(const f32x4*)(p + 4);
        }
        bf16x8 bv[4];
        #pragma unroll
        for (int t = 0; t < 4; ++t) {
            int row = srow + t * 32;
            bv[t] = *(const bf16x8*)(Wt + (nBase + row) * KDIM + kk * BK + sc * 8);
        }

        __syncthreads();   // previous compute done reading LDS

        // ---- convert + ds_write (swizzled) ----
        #pragma unroll
        for (int t = 0; t < 4; ++t) {
            int row  = srow + t * 32;
            int byte = row * (BK * 2) + sc * 16;
            byte ^= (row & 7) << 4;
            bf16x8 v;
            v[0] = f2b(ax[t][0]); v[1] = f2b(ax[t][1]);
            v[2] = f2b(ax[t][2]); v[3] = f2b(ax[t][3]);
            v[4] = f2b(ay[t][0]); v[5] = f2b(ay[t][1]);
            v[6] = f2b(ay[t][2]); v[7] = f2b(ay[t][3]);
            *(bf16x8*)(Ab + byte) = v;
            *(bf16x8*)(Bb + byte) = bv[t];
        }

        __syncthreads();

        // ---- compute: 2 k-steps of 32 ----
        #pragma unroll
        for (int ks = 0; ks < 2; ++ks) {
            const int cb = ks * 4 + g;   // 16B chunk index along k
            bf16x8 ef[4], wf[4];
            #pragma unroll
            for (int mf = 0; mf < 4; ++mf) {
                int row  = wm * 64 + mf * 16 + r;
                int byte = row * (BK * 2) + cb * 16;
                byte ^= (row & 7) << 4;
                ef[mf] = *(const bf16x8*)(Ab + byte);
            }
            #pragma unroll
            for (int nf = 0; nf < 4; ++nf) {
                int row  = wn * 64 + nf * 16 + r;
                int byte = row * (BK * 2) + cb * 16;
                byte ^= (row & 7) << 4;
                wf[nf] = *(const bf16x8*)(Bb + byte);
            }
            #pragma unroll
            for (int nf = 0; nf < 4; ++nf)
                #pragma unroll
                for (int mf = 0; mf < 4; ++mf)
                    acc[nf][mf] = __builtin_amdgcn_mfma_f32_16x16x32_bf16(
                        wf[nf], ef[mf], acc[nf][mf], 0, 0, 0);
        }
    }

    // ---- epilogue: D[row=n_local(g*4+i)][col=m_local(r)]; per-lane float4 along n ----
    #pragma unroll
    for (int nf = 0; nf < 4; ++nf) {
        int n = nBase + wn * 64 + nf * 16 + g * 4;
        f32x4 bb = *(const f32x4*)(bias + n);
        #pragma unroll
        for (int mf = 0; mf < 4; ++mf) {
            int m = mBase + wm * 64 + mf * 16 + r;
            f32x4 v = acc[nf][mf] + bb;
            *(f32x4*)(out + (size_t)m * NOUT + n) = v;
        }
    }
}

extern "C" void kernel_launch(void* const* d_in, const int* in_sizes, int n_in,
                              void* d_out, int out_size, void* d_ws, size_t ws_size,
                              hipStream_t stream) {
    const float* h_node = (const float*)d_in[0];
    const float* h_edge = (const float*)d_in[1];
    const int*   pl     = (const int*)d_in[2];
    const float* W      = (const float*)d_in[3];
    const float* bias   = (const float*)d_in[4];
    float* out = (float*)d_out;
    short* Wt  = (short*)d_ws;   // 768*384*2 = 589824 B

    prep_kernel<<<NOUT, 256, 0, stream>>>(W, Wt);
    gemm_kernel<<<1024 * 6, 256, 0, stream>>>(h_node, h_edge, pl, Wt, bias, out);
}

// Round 4
// 636.147 us; speedup vs baseline: 1.0436x; 1.0436x over previous
//
#include <hip/hip_runtime.h>

// SGGM: out[131072,768] = concat(h_node[b,i], h_node[b,j], h_edge[b,i,j]) @ W + bias
// B=32, N=128, H=128, E_PER=4096 -> M=131072, K=384, NOUT=768
// R2 design (resubmitted; R3 was an acquisition timeout):
//   2-phase pipeline (1 barrier/iter), XCD-chunked n-sibling dispatch,
//   B via global_load_lds from pre-swizzled WtS.

#define NNODE 128
#define HDIM  128
#define KDIM  384
#define NOUT  768
#define BM    128
#define BN    128
#define BK    64
#define NKITER 6   // 384/64

typedef __attribute__((ext_vector_type(4))) float f32x4;
typedef __attribute__((ext_vector_type(8))) short bf16x8;

static __device__ __forceinline__ short f2b(float f) {
    return __builtin_bit_cast(short, (__bf16)f);  // v_cvt RNE
}

static __device__ __forceinline__ void gload_lds16(const void* g, void* l) {
    __builtin_amdgcn_global_load_lds((const __attribute__((address_space(1))) void*)g,
                                     (__attribute__((address_space(3))) void*)l, 16, 0, 0);
}

// WtS: 36 tiles (nb*6+kk), each 1024 chunks of 16B. Chunk c holds
// row = c>>3, kb = (c&7)^(row&7):  bf16(W[kk*64+kb*8+e][nb*128+row]), e=0..7.
// Then glds-linear LDS placement satisfies: lds_byte(row,kb) = row*128 + (kb*16 ^ ((row&7)<<4)).
__global__ void prep_kernel(const float* __restrict__ W, short* __restrict__ WtS) {
    int gid  = blockIdx.x * 256 + threadIdx.x;   // 36864 = 36*1024
    int tile = gid >> 10;
    int c    = gid & 1023;
    int nb   = tile / 6, kk = tile - nb * 6;
    int row  = c >> 3;
    int kb   = (c & 7) ^ (row & 7);
    int n    = nb * 128 + row;
    int k0   = kk * 64 + kb * 8;
    short v[8];
    #pragma unroll
    for (int e = 0; e < 8; ++e) v[e] = f2b(W[(k0 + e) * NOUT + n]);
    *(bf16x8*)(WtS + (size_t)gid * 8) = *(bf16x8*)v;
}

__global__ __launch_bounds__(256) void gemm_kernel(
    const float* __restrict__ h_node, const float* __restrict__ h_edge,
    const int* __restrict__ pl, const short* __restrict__ WtS,
    const float* __restrict__ bias, float* __restrict__ out) {

    __shared__ int rowOff[3][BM];
    __shared__ __align__(16) short Abuf[2][BM * BK];  // 2x16KB, XOR-swizzled
    __shared__ __align__(16) short Bbuf[2][BN * BK];  // 2x16KB, glds-linear+pre-swz

    const int tid = threadIdx.x;
    const int bid = blockIdx.x;
    // XCD-chunked: 6 n-siblings of each m-block adjacent on the same XCD -> A reused in L2
    const int xcd = bid & 7;
    const int idx = bid >> 3;            // 0..767
    const int mBase = (xcd * 128 + idx / 6) * BM;
    const int nb    = idx % 6;
    const int nBase = nb * BN;
    const int nb6   = nb * 6;

    if (tid < BM) {
        int e  = pl ? mBase + tid : 0;
        int b  = pl[3 * (mBase + tid) + 0];
        int ii = pl[3 * (mBase + tid) + 1];
        int jj = pl[3 * (mBase + tid) + 2];
        (void)e;
        rowOff[0][tid] = (b * NNODE + ii) * HDIM;
        rowOff[1][tid] = (b * NNODE + jj) * HDIM;
        rowOff[2][tid] = ((b * NNODE + ii) * NNODE + jj) * HDIM;
    }
    __syncthreads();

    const int lane = tid & 63;
    const int wid  = tid >> 6;
    const int wm   = wid & 1;
    const int wn   = wid >> 1;
    const int r    = lane & 15;
    const int g    = lane >> 4;
    const int srow = tid >> 3;   // staging row base (rows srow + t*32)
    const int sc   = tid & 7;    // 16B chunk within 64-elem row

    // hoist gather offsets into registers (static indexing only)
    int ro[3][4];
    #pragma unroll
    for (int s = 0; s < 3; ++s)
        #pragma unroll
        for (int t = 0; t < 4; ++t)
            ro[s][t] = rowOff[s][srow + t * 32];

    f32x4 acc[4][4];
    #pragma unroll
    for (int a = 0; a < 4; ++a)
        #pragma unroll
        for (int b2 = 0; b2 < 4; ++b2)
            acc[a][b2] = (f32x4){0.f, 0.f, 0.f, 0.f};

    f32x4 a0[4], a1[4];

    auto issueA = [&](int kt) {
        const int seg  = kt >> 1;
        const float* gb = (seg < 2) ? h_node : h_edge;
        const int koff = (kt & 1) * BK;
        #pragma unroll
        for (int t = 0; t < 4; ++t) {
            const float* p = gb + ro[seg][t] + koff + sc * 8;
            a0[t] = *(const f32x4*)p;
            a1[t] = *(const f32x4*)(p + 4);
        }
    };
    auto issueB = [&](int kt, int buf) {
        const short* src = WtS + (size_t)((nb6 + kt) << 10) * 8;
        short* ldsb = &Bbuf[buf][0];
        #pragma unroll
        for (int i = 0; i < 4; ++i) {
            int cb0 = wid * 256 + i * 64;   // wave-uniform chunk base
            gload_lds16(src + (size_t)(cb0 + lane) * 8, ldsb + cb0 * 8);
        }
    };
    auto writeA = [&](int buf) {
        char* Ab = (char*)&Abuf[buf][0];
        #pragma unroll
        for (int t = 0; t < 4; ++t) {
            int row  = srow + t * 32;
            int byte = (row * 128 + sc * 16) ^ ((row & 7) << 4);
            bf16x8 v;
            v[0] = f2b(a0[t][0]); v[1] = f2b(a0[t][1]);
            v[2] = f2b(a0[t][2]); v[3] = f2b(a0[t][3]);
            v[4] = f2b(a1[t][0]); v[5] = f2b(a1[t][1]);
            v[6] = f2b(a1[t][2]); v[7] = f2b(a1[t][3]);
            *(bf16x8*)(Ab + byte) = v;
        }
    };
    auto compute = [&](int buf) {
        char* Ab = (char*)&Abuf[buf][0];
        char* Bb = (char*)&Bbuf[buf][0];
        #pragma unroll
        for (int ks = 0; ks < 2; ++ks) {
            const int cb = ks * 4 + g;
            bf16x8 ef[4], wf[4];
            #pragma unroll
            for (int mf = 0; mf < 4; ++mf) {
                int row  = wm * 64 + mf * 16 + r;
                int byte = (row * 128 + cb * 16) ^ ((row & 7) << 4);
                ef[mf] = *(const bf16x8*)(Ab + byte);
            }
            #pragma unroll
            for (int nf = 0; nf < 4; ++nf) {
                int row  = wn * 64 + nf * 16 + r;
                int byte = (row * 128 + cb * 16) ^ ((row & 7) << 4);
                wf[nf] = *(const bf16x8*)(Bb + byte);
            }
            #pragma unroll
            for (int nf = 0; nf < 4; ++nf)
                #pragma unroll
                for (int mf = 0; mf < 4; ++mf)
                    acc[nf][mf] = __builtin_amdgcn_mfma_f32_16x16x32_bf16(
                        wf[nf], ef[mf], acc[nf][mf], 0, 0, 0);
        }
    };

    // ---- prologue: stage tile 0 ----
    issueA(0);
    issueB(0, 0);
    asm volatile("s_waitcnt vmcnt(0)" ::: "memory");  // A regs + B glds landed
    writeA(0);
    __syncthreads();

    // ---- main loop: 1 barrier/iter; next-tile loads fly under compute ----
    int cur = 0;
    #pragma unroll
    for (int t = 0; t < NKITER; ++t) {
        if (t + 1 < NKITER) {
            issueA(t + 1);
            issueB(t + 1, cur ^ 1);
        }
        compute(cur);
        if (t + 1 < NKITER) {
            asm volatile("s_waitcnt vmcnt(0)" ::: "memory");  // drain A regs + B glds
            writeA(cur ^ 1);
            __syncthreads();
        }
        cur ^= 1;
    }

    // ---- epilogue: D row = n_local (g*4+i), col = m_local (r) ----
    #pragma unroll
    for (int nf = 0; nf < 4; ++nf) {
        int n = nBase + wn * 64 + nf * 16 + g * 4;
        f32x4 bb = *(const f32x4*)(bias + n);
        #pragma unroll
        for (int mf = 0; mf < 4; ++mf) {
            int m = mBase + wm * 64 + mf * 16 + r;
            f32x4 v = acc[nf][mf] + bb;
            *(f32x4*)(out + (size_t)m * NOUT + n) = v;
        }
    }
}

extern "C" void kernel_launch(void* const* d_in, const int* in_sizes, int n_in,
                              void* d_out, int out_size, void* d_ws, size_t ws_size,
                              hipStream_t stream) {
    const float* h_node = (const float*)d_in[0];
    const float* h_edge = (const float*)d_in[1];
    const int*   pl     = (const int*)d_in[2];
    const float* W      = (const float*)d_in[3];
    const float* bias   = (const float*)d_in[4];
    float* out = (float*)d_out;
    short* WtS = (short*)d_ws;   // 36*1024*16 B = 589824 B

    prep_kernel<<<144, 256, 0, stream>>>(W, WtS);   // 144*256 = 36864 chunks
    gemm_kernel<<<1024 * 6, 256, 0, stream>>>(h_node, h_edge, pl, WtS, bias, out);
}